// Round 10
// baseline (837.205 us; speedup 1.0000x reference)
//
#include <hip/hip_runtime.h>

// Problem constants (B=4, T=8, N=2048, C=64)
#define BB 4
#define TT 8
#define NN 2048
#define CC 64
#define MM 512           // N / SPATIAL_STRIDE
#define KK 32
#define H3DIM 256
#define RAD2 0.25f
#define FINF 3.4e38f

typedef _Float16 f16x8 __attribute__((ext_vector_type(8)));
typedef _Float16 f16x4 __attribute__((ext_vector_type(4)));
typedef float f32x4 __attribute__((ext_vector_type(4)));

// ---------------------------------------------------------------------------
// f32 DPP wave-64 max tree (row_shr 1/2/4/8 + row_bcast15/31, result lane 63).
// HW-validated rounds 2-9.
// ---------------------------------------------------------------------------
template <int CTRL>
__device__ __forceinline__ float dpp_max_step(float x) {
    int xi = __builtin_bit_cast(int, x);
    int yi = __builtin_amdgcn_update_dpp(xi, xi, CTRL, 0xf, 0xf, false);
    return fmaxf(x, __builtin_bit_cast(float, yi));
}
__device__ __forceinline__ float wave_max64(float x) {
    x = dpp_max_step<0x111>(x);
    x = dpp_max_step<0x112>(x);
    x = dpp_max_step<0x114>(x);
    x = dpp_max_step<0x118>(x);
    x = dpp_max_step<0x142>(x);
    x = dpp_max_step<0x143>(x);
    return __builtin_bit_cast(float, __builtin_amdgcn_readlane(__builtin_bit_cast(int, x), 63));
}
// Packed u64 DPP min (validated rounds 8/9 in k_knn).
template <int CTRL>
__device__ __forceinline__ unsigned long long dpp_minkey_step(unsigned long long k) {
    int lo = (int)(unsigned)k;
    int hi = (int)(unsigned)(k >> 32);
    int slo = __builtin_amdgcn_update_dpp(lo, lo, CTRL, 0xf, 0xf, false);
    int shi = __builtin_amdgcn_update_dpp(hi, hi, CTRL, 0xf, 0xf, false);
    unsigned long long s = ((unsigned long long)(unsigned)shi << 32) | (unsigned)slo;
    return s < k ? s : k;
}
__device__ __forceinline__ unsigned long long wave_minkey(unsigned long long k) {
    k = dpp_minkey_step<0x111>(k);
    k = dpp_minkey_step<0x112>(k);
    k = dpp_minkey_step<0x114>(k);
    k = dpp_minkey_step<0x118>(k);
    k = dpp_minkey_step<0x142>(k);
    k = dpp_minkey_step<0x143>(k);
    int lo = __builtin_amdgcn_readlane((int)(unsigned)k, 63);
    int hi = __builtin_amdgcn_readlane((int)(unsigned)(k >> 32), 63);
    return ((unsigned long long)(unsigned)hi << 32) | (unsigned)lo;
}

// ---------------------------------------------------------------------------
// Kernel 1: farthest point sampling. 4 INDEPENDENT clouds per block
// (1024 thr, 16 waves, 4 waves/SIMD -> latency hiding across clouds).
// Per cloud: 256 threads, 8 pts/thread (tid-major => tie order preserved).
// Scan carries winner coords incrementally (no post-hoc select tree);
// winner lane self-identifies from ballot mask and writes {x,y,z,d}+p;
// combine tree gives next cur coords directly (no sx[cur] refetch).
// Dynamic LDS: xyz[4][2048]*3 = 96KB + records.
// ---------------------------------------------------------------------------
#define FPS_XYZ_F (4 * NN)                 // floats per coord plane
#define FPS_REC_OFF (3 * FPS_XYZ_F * 4)    // 98304 B
#define FPS_LDS (FPS_REC_OFF + 2 * 16 * 16 + 2 * 16 * 4)   // + recx 512B + recp 128B

__global__ __launch_bounds__(1024) void k_fps(const float* __restrict__ xyzs,
                                              int* __restrict__ fps_idx) {
    extern __shared__ char fsm[];
    float* sx = (float*)fsm;
    float* sy = sx + FPS_XYZ_F;
    float* sz = sy + FPS_XYZ_F;
    float4* recx = (float4*)(fsm + FPS_REC_OFF);        // [2][4cl][4w]
    int* recp = (int*)(fsm + FPS_REC_OFF + 2 * 16 * 16); // [2][4cl][4w]

    int tid = threadIdx.x;
    int cl = tid >> 8, ctid = tid & 255;
    int lane = tid & 63, wc = (tid >> 6) & 3;
    int cloud = blockIdx.x * 4 + cl;

    const float* src = xyzs + (size_t)cloud * NN * 3;
    for (int i = ctid; i < NN; i += 256) {
        sx[cl * NN + i] = src[i * 3 + 0];
        sy[cl * NN + i] = src[i * 3 + 1];
        sz[cl * NN + i] = src[i * 3 + 2];
    }
    __syncthreads();

    float px[8], py[8], pz[8], dist[8];
#pragma unroll
    for (int j = 0; j < 8; ++j) {
        int p = ctid * 8 + j;
        px[j] = sx[cl * NN + p]; py[j] = sy[cl * NN + p]; pz[j] = sz[cl * NN + p];
        dist[j] = 1e10f;
    }

    if (ctid == 0) fps_idx[cloud * MM + 0] = 0;
    int pbase = ctid * 8;
    float cx = sx[cl * NN], cy = sy[cl * NN], cz = sz[cl * NN];

    for (int it = 1; it < MM; ++it) {
        // distance update (exact expression, rounds 1-9)
        float nd[8];
#pragma unroll
        for (int j = 0; j < 8; ++j) {
            float dx = px[j] - cx, dy = py[j] - cy, dz = pz[j] - cz;
            float d = dx * dx + dy * dy + dz * dz;
            nd[j] = fminf(dist[j], d);
            dist[j] = nd[j];
        }
        // lane argmax, coords carried (2 groups of 4 + tree; strict > = smallest j)
        float gd0 = nd[0], gx0 = px[0], gy0 = py[0], gz0 = pz[0]; int gp0 = pbase;
#pragma unroll
        for (int j = 1; j < 4; ++j)
            if (nd[j] > gd0) { gd0 = nd[j]; gp0 = pbase + j; gx0 = px[j]; gy0 = py[j]; gz0 = pz[j]; }
        float gd1 = nd[4], gx1 = px[4], gy1 = py[4], gz1 = pz[4]; int gp1 = pbase + 4;
#pragma unroll
        for (int j = 5; j < 8; ++j)
            if (nd[j] > gd1) { gd1 = nd[j]; gp1 = pbase + j; gx1 = px[j]; gy1 = py[j]; gz1 = pz[j]; }
        bool gt = gd1 > gd0;                 // strict: group0 wins ties (smaller j)
        float bestd = gt ? gd1 : gd0;
        int   bestp = gt ? gp1 : gp0;
        float bx = gt ? gx1 : gx0;
        float by = gt ? gy1 : gy0;
        float bz = gt ? gz1 : gz0;
        // wave argmax: f32 DPP max + ballot; lowest tied lane self-identifies
        float wmax = wave_max64(bestd);
        unsigned long long mask = __ballot(bestd == wmax);
        unsigned long long lower = mask & ((1ull << lane) - 1ull);
        if ((bestd == wmax) && lower == 0ull) {
            float4 r; r.x = bx; r.y = by; r.z = bz; r.w = wmax;
            recx[(it & 1) * 16 + cl * 4 + wc] = r;
            recp[(it & 1) * 16 + cl * 4 + wc] = bestp;
        }
        __syncthreads();
        // combine own cloud's 4 wave records (strict >, earlier wave wins ties)
        int rb_ = (it & 1) * 16 + cl * 4;
        float4 r0 = recx[rb_ + 0];
        float4 r1 = recx[rb_ + 1];
        float4 r2 = recx[rb_ + 2];
        float4 r3 = recx[rb_ + 3];
        int4 pv = *(const int4*)&recp[rb_];
        bool t01 = r1.w > r0.w, t23 = r3.w > r2.w;
        float4 ra = t01 ? r1 : r0; int pa = t01 ? pv.y : pv.x;
        float4 rb = t23 ? r3 : r2; int pb = t23 ? pv.w : pv.z;
        bool tf = rb.w > ra.w;
        float4 rf = tf ? rb : ra;
        int pf = tf ? pb : pa;
        cx = rf.x; cy = rf.y; cz = rf.z;
        if (ctid == 0) fps_idx[cloud * MM + it] = pf;
    }
}

// ---------------------------------------------------------------------------
// Kernel 2a: P'[row,c] (fp16) = feat_n.W1[0:64] + xyz_n.W1[128:131]
// (unchanged — verified)
// ---------------------------------------------------------------------------
__global__ __launch_bounds__(256) void k_pp(const float* __restrict__ xyzs,
                                            const float* __restrict__ feats,
                                            const float* __restrict__ w1,
                                            _Float16* __restrict__ Pp) {
    __shared__ float sw[68 * 128];
    __shared__ float sin_[64 * 68];
    int tid = threadIdx.x;
    for (int i = tid; i < 68 * 128; i += 256) {
        int r = i >> 7, c = i & 127;
        float v = 0.f;
        if (r < 64) v = w1[r * 128 + c];
        else if (r < 67) v = w1[(128 + r - 64) * 128 + c];
        sw[i] = v;
    }
    int row0 = blockIdx.x * 64;
    int bt = row0 >> 11;
    int b = bt >> 3, t = bt & 7;
    int tn = (t + 1 < TT) ? (t + 1) : (TT - 1);
    size_t nbase = (size_t)(b * TT + tn) * NN + (row0 & (NN - 1));
    const float* fsrc = feats + nbase * CC;
    const float* xsrc = xyzs + nbase * 3;
    for (int i = tid; i < 1024; i += 256) {
        float4 v = ((const float4*)fsrc)[i];
        int r = i >> 4, c = (i & 15) * 4;
        *(float4*)&sin_[r * 68 + c] = v;
    }
    if (tid < 192) {
        int r = tid / 3, c = tid - r * 3;
        sin_[r * 68 + 64 + c] = xsrc[tid];
    }
    if (tid < 64) sin_[tid * 68 + 67] = 0.f;
    __syncthreads();

    int rowg = tid >> 5, colg = tid & 31;
    float4 acc[8];
#pragma unroll
    for (int i = 0; i < 8; ++i) acc[i] = make_float4(0.f, 0.f, 0.f, 0.f);
    for (int k = 0; k < 68; k += 4) {
        float4 a4[8], b4[4];
#pragma unroll
        for (int i = 0; i < 8; ++i) a4[i] = *(const float4*)&sin_[(rowg * 8 + i) * 68 + k];
#pragma unroll
        for (int kk = 0; kk < 4; ++kk) b4[kk] = *(const float4*)&sw[(k + kk) * 128 + colg * 4];
#pragma unroll
        for (int i = 0; i < 8; ++i) {
#pragma unroll
            for (int kk = 0; kk < 4; ++kk) {
                float av = (kk == 0) ? a4[i].x : (kk == 1) ? a4[i].y : (kk == 2) ? a4[i].z : a4[i].w;
                acc[i].x += av * b4[kk].x;
                acc[i].y += av * b4[kk].y;
                acc[i].z += av * b4[kk].z;
                acc[i].w += av * b4[kk].w;
            }
        }
    }
#pragma unroll
    for (int i = 0; i < 8; ++i) {
        f16x4 h;
        h[0] = (_Float16)acc[i].x; h[1] = (_Float16)acc[i].y;
        h[2] = (_Float16)acc[i].z; h[3] = (_Float16)acc[i].w;
        *(f16x4*)&Pp[(size_t)(row0 + rowg * 8 + i) * 128 + colg * 4] = h;
    }
}

// ---------------------------------------------------------------------------
// Kernel 2b: Q' + anchors. (unchanged — verified)
// ---------------------------------------------------------------------------
__global__ __launch_bounds__(256) void k_qp(const float* __restrict__ xyzs,
                                            const float* __restrict__ feats,
                                            const float* __restrict__ w1,
                                            const float* __restrict__ b1,
                                            const int* __restrict__ fps_idx,
                                            float* __restrict__ Qp,
                                            float* __restrict__ out_anchor) {
    __shared__ float sw[68 * 128];
    __shared__ float sin_[64 * 68];
    __shared__ float sb[128];
    int tid = threadIdx.x;
    for (int i = tid; i < 68 * 128; i += 256) {
        int r = i >> 7, c = i & 127;
        float v = 0.f;
        if (r < 64) v = w1[(64 + r) * 128 + c];
        else if (r < 67) v = w1[(128 + r - 64) * 128 + c];
        sw[i] = v;
    }
    if (tid < 128) sb[tid] = b1[tid];
    int row0 = blockIdx.x * 64;
    int bt = row0 >> 9;
    size_t fbase = (size_t)bt * NN;
    {
        int r = tid >> 2, seg = tid & 3;
        int aidx = fps_idx[row0 + r];
        const float4* fr = (const float4*)(feats + (fbase + aidx) * CC);
#pragma unroll
        for (int i = 0; i < 4; ++i) {
            float4 v = fr[seg * 4 + i];
            *(float4*)&sin_[r * 68 + seg * 16 + i * 4] = v;
        }
    }
    if (tid < 64) {
        int aidx = fps_idx[row0 + tid];
        const float* xs = xyzs + (fbase + aidx) * 3;
        float x = xs[0], y = xs[1], z = xs[2];
        sin_[tid * 68 + 64] = -x;
        sin_[tid * 68 + 65] = -y;
        sin_[tid * 68 + 66] = -z;
        sin_[tid * 68 + 67] = 0.f;
        out_anchor[(size_t)(row0 + tid) * 3 + 0] = x;
        out_anchor[(size_t)(row0 + tid) * 3 + 1] = y;
        out_anchor[(size_t)(row0 + tid) * 3 + 2] = z;
    }
    __syncthreads();

    int rowg = tid >> 5, colg = tid & 31;
    float4 bias = *(const float4*)&sb[colg * 4];
    float4 acc[8];
#pragma unroll
    for (int i = 0; i < 8; ++i) acc[i] = bias;
    for (int k = 0; k < 68; k += 4) {
        float4 a4[8], b4[4];
#pragma unroll
        for (int i = 0; i < 8; ++i) a4[i] = *(const float4*)&sin_[(rowg * 8 + i) * 68 + k];
#pragma unroll
        for (int kk = 0; kk < 4; ++kk) b4[kk] = *(const float4*)&sw[(k + kk) * 128 + colg * 4];
#pragma unroll
        for (int i = 0; i < 8; ++i) {
#pragma unroll
            for (int kk = 0; kk < 4; ++kk) {
                float av = (kk == 0) ? a4[i].x : (kk == 1) ? a4[i].y : (kk == 2) ? a4[i].z : a4[i].w;
                acc[i].x += av * b4[kk].x;
                acc[i].y += av * b4[kk].y;
                acc[i].z += av * b4[kk].z;
                acc[i].w += av * b4[kk].w;
            }
        }
    }
#pragma unroll
    for (int i = 0; i < 8; ++i)
        *(float4*)&Qp[(size_t)(row0 + rowg * 8 + i) * 128 + colg * 4] = acc[i];
}

// ---------------------------------------------------------------------------
// Kernel 3: exact stable top-K=32 nearest + radius filter.
// (unchanged from rounds 8/9 — verified)
// ---------------------------------------------------------------------------
__global__ __launch_bounds__(256) void k_knn(const float* __restrict__ xyzs,
                                             const float* __restrict__ anchors,
                                             int* __restrict__ idxk) {
    __shared__ float sx[NN], sy[NN], sz[NN];
    int tid = threadIdx.x;
    int wave = tid >> 6, lane = tid & 63;
    int bt = blockIdx.x >> 6;              // 64 blocks per (b,t)
    int sub = blockIdx.x & 63;
    int b = bt >> 3, t = bt & 7;
    int tn = (t + 1 < TT) ? (t + 1) : (TT - 1);
    const float* src = xyzs + ((size_t)(b * TT + tn)) * NN * 3;
    for (int i = tid; i < NN; i += 256) {
        sx[i] = src[i * 3 + 0];
        sy[i] = src[i * 3 + 1];
        sz[i] = src[i * 3 + 2];
    }
    __syncthreads();

    for (int a = 0; a < 2; ++a) {
        int mrow = bt * MM + sub * 8 + wave * 2 + a;
        float ax = anchors[mrow * 3 + 0];
        float ay = anchors[mrow * 3 + 1];
        float az = anchors[mrow * 3 + 2];
        float d[32];
#pragma unroll
        for (int j = 0; j < 32; ++j) {
            int p = j * 64 + lane;
            float dx = sx[p] - ax, dy = sy[p] - ay, dz = sz[p] - az;
            d[j] = dx * dx + dy * dy + dz * dz;
        }
        int p0 = 0;
        int myidx = 0;
        for (int r = 0; r < KK; ++r) {
            float gd[4];
            int gp[4];
#pragma unroll
            for (int g = 0; g < 4; ++g) {
                gd[g] = d[g * 8];
                gp[g] = (g * 8) * 64 + lane;
#pragma unroll
                for (int jj = 1; jj < 8; ++jj) {
                    float dj = d[g * 8 + jj];
                    if (dj < gd[g]) { gd[g] = dj; gp[g] = (g * 8 + jj) * 64 + lane; }  // strict <
                }
            }
            bool u01 = gd[1] < gd[0], u23 = gd[3] < gd[2];
            float da = u01 ? gd[1] : gd[0], db = u23 ? gd[3] : gd[2];
            int pa = u01 ? gp[1] : gp[0], pb = u23 ? gp[3] : gp[2];
            bool uf = db < da;
            float bd = uf ? db : da;
            int bp = uf ? pb : pa;
            unsigned long long key =
                ((unsigned long long)(unsigned)__builtin_bit_cast(unsigned, bd) << 32) |
                (unsigned)bp;
            unsigned long long wkey = wave_minkey(key);
            int pstar = (int)(unsigned)wkey;
            float dstar = __builtin_bit_cast(float, (unsigned)(wkey >> 32));
            if (r == 0) { p0 = pstar; myidx = pstar; }
            int outp = (dstar <= RAD2) ? pstar : p0;   // radius replacement
            if (lane == r) myidx = outp;
            if (r < KK - 1) {
                int lanew = pstar & 63;                 // uniform (SGPR)
                int jw = pstar >> 6;                    // uniform (SGPR)
                bool imw = (lane == lanew);
#pragma unroll
                for (int j = 0; j < 32; ++j)
                    d[j] = (imw && j == jw) ? FINF : d[j];
            }
        }
        if (lane < KK) idxk[(size_t)mrow * KK + lane] = myidx;
    }
}

// ---------------------------------------------------------------------------
// Kernel 4: persistent-block fp16 MFMA MLP (layers 2+3) + max over K.
// (unchanged — verified; 512 thr / 8 waves)
// ---------------------------------------------------------------------------
#define SM_W2 0
#define SM_W3 32768
#define SM_H1 98304
#define SM_H2 114688
#define SM_B2 131072
#define SM_B3 131584
#define SM_TOTAL 132608

__global__ __launch_bounds__(512, 1) void k_mlp(const _Float16* __restrict__ Pp,
                                                const float* __restrict__ Qp,
                                                const int* __restrict__ idxk,
                                                const float* __restrict__ w2,
                                                const float* __restrict__ b2,
                                                const float* __restrict__ w3,
                                                const float* __restrict__ b3,
                                                float* __restrict__ out_feat) {
    extern __shared__ char smem[];
    int tid = threadIdx.x;
    int bid = blockIdx.x;                  // 0..255

    for (int i = tid; i < 128 * 128; i += 512) {
        int n = i & 127, kk = i >> 7;
        _Float16 v = (_Float16)w2[kk * 128 + n];
        *(_Float16*)(smem + SM_W2 + n * 256 + ((2 * kk) ^ ((n & 7) << 4))) = v;
    }
    for (int i = tid; i < 256 * 128; i += 512) {
        int n = i & 255, kk = i >> 8;
        _Float16 v = (_Float16)w3[kk * 256 + n];
        *(_Float16*)(smem + SM_W3 + n * 256 + ((2 * kk) ^ ((n & 7) << 4))) = v;
    }
    if (tid < 128) *(float*)(smem + SM_B2 + tid * 4) = b2[tid];
    if (tid < 256) *(float*)(smem + SM_B3 + tid * 4) = b3[tid];
    __syncthreads();

    int lane = tid & 63;
    int w = tid >> 6;                      // 0..7
    int wm = w >> 2, wn = w & 3;           // 2 anchors x 4 col-groups
    int l15 = lane & 15, g = lane >> 4;
    int hswz = (l15 & 7) << 4;

    const f32x4 zero4 = {0.f, 0.f, 0.f, 0.f};

    for (int c = 0; c < 32; ++c) {
        int a0 = bid * 64 + c * 2;
        int bt = a0 >> 9;

        {
            int r = tid >> 3, seg = tid & 7;
            int arow = a0 + (r >> 5);
            int kidx = r & 31;
            int nk = idxk[(size_t)arow * KK + kidx];
            const _Float16* ps = Pp + ((size_t)(bt * NN + nk)) * 128 + seg * 16;
            const float* qs = Qp + (size_t)arow * 128 + seg * 16;
            int rowbase = SM_H1 + r * 256;
            int swz = (r & 7) << 4;
#pragma unroll
            for (int i = 0; i < 2; ++i) {
                f16x8 pv = *(const f16x8*)(ps + i * 8);
                f32x4 q0 = *(const f32x4*)(qs + i * 8);
                f32x4 q1 = *(const f32x4*)(qs + i * 8 + 4);
                f16x8 hv;
#pragma unroll
                for (int j = 0; j < 4; ++j) hv[j] = (_Float16)fmaxf((float)pv[j] + q0[j], 0.f);
#pragma unroll
                for (int j = 0; j < 4; ++j) hv[4 + j] = (_Float16)fmaxf((float)pv[4 + j] + q1[j], 0.f);
                *(f16x8*)(smem + rowbase + ((seg * 32 + i * 16) ^ swz)) = hv;
            }
        }
        __syncthreads();

        f32x4 acc2[2][2];
#pragma unroll
        for (int m = 0; m < 2; ++m)
#pragma unroll
            for (int n = 0; n < 2; ++n) acc2[m][n] = zero4;

#pragma unroll
        for (int ks = 0; ks < 4; ++ks) {
            int kbyte = ks * 64 + g * 16;
            f16x8 af[2], bf[2];
#pragma unroll
            for (int m = 0; m < 2; ++m) {
                int row = wm * 32 + m * 16 + l15;
                af[m] = *(const f16x8*)(smem + SM_H1 + row * 256 + (kbyte ^ hswz));
            }
#pragma unroll
            for (int n = 0; n < 2; ++n) {
                int col = wn * 32 + n * 16 + l15;
                bf[n] = *(const f16x8*)(smem + SM_W2 + col * 256 + (kbyte ^ hswz));
            }
#pragma unroll
            for (int m = 0; m < 2; ++m)
#pragma unroll
                for (int n = 0; n < 2; ++n)
                    acc2[m][n] = __builtin_amdgcn_mfma_f32_16x16x32_f16(af[m], bf[n], acc2[m][n], 0, 0, 0);
        }
#pragma unroll
        for (int m = 0; m < 2; ++m)
#pragma unroll
            for (int n = 0; n < 2; ++n) {
                int col = wn * 32 + n * 16 + l15;
                float bb = *(const float*)(smem + SM_B2 + col * 4);
#pragma unroll
                for (int r = 0; r < 4; ++r) {
                    int row = wm * 32 + m * 16 + g * 4 + r;
                    float v = fmaxf(acc2[m][n][r] + bb, 0.f);
                    *(_Float16*)(smem + SM_H2 + row * 256 + ((2 * col) ^ ((row & 7) << 4))) = (_Float16)v;
                }
            }
        __syncthreads();

        f32x4 acc3[2][4];
#pragma unroll
        for (int m = 0; m < 2; ++m)
#pragma unroll
            for (int n = 0; n < 4; ++n) acc3[m][n] = zero4;

#pragma unroll
        for (int ks = 0; ks < 4; ++ks) {
            int kbyte = ks * 64 + g * 16;
            f16x8 af[2], bf[4];
#pragma unroll
            for (int m = 0; m < 2; ++m) {
                int row = wm * 32 + m * 16 + l15;
                af[m] = *(const f16x8*)(smem + SM_H2 + row * 256 + (kbyte ^ hswz));
            }
#pragma unroll
            for (int n = 0; n < 4; ++n) {
                int col = wn * 64 + n * 16 + l15;
                bf[n] = *(const f16x8*)(smem + SM_W3 + col * 256 + (kbyte ^ hswz));
            }
#pragma unroll
            for (int m = 0; m < 2; ++m)
#pragma unroll
                for (int n = 0; n < 4; ++n)
                    acc3[m][n] = __builtin_amdgcn_mfma_f32_16x16x32_f16(af[m], bf[n], acc3[m][n], 0, 0, 0);
        }
#pragma unroll
        for (int n = 0; n < 4; ++n) {
            int col = wn * 64 + n * 16 + l15;
            float s = acc3[0][n][0];
#pragma unroll
            for (int r = 1; r < 4; ++r) s = fmaxf(s, acc3[0][n][r]);
#pragma unroll
            for (int r = 0; r < 4; ++r) s = fmaxf(s, acc3[1][n][r]);
            s = fmaxf(s, __shfl_xor(s, 16));
            s = fmaxf(s, __shfl_xor(s, 32));
            if (g == 0) {
                float bb = *(const float*)(smem + SM_B3 + col * 4);
                out_feat[(size_t)(a0 + wm) * H3DIM + col] = fmaxf(s + bb, 0.f);
            }
        }
        __syncthreads();
    }
}

// ---------------------------------------------------------------------------
extern "C" void kernel_launch(void* const* d_in, const int* in_sizes, int n_in,
                              void* d_out, int out_size, void* d_ws, size_t ws_size,
                              hipStream_t stream) {
    const float* xyzs  = (const float*)d_in[0];
    const float* feats = (const float*)d_in[1];
    const float* w1 = (const float*)d_in[2];
    const float* b1 = (const float*)d_in[3];
    const float* w2 = (const float*)d_in[4];
    const float* b2 = (const float*)d_in[5];
    const float* w3 = (const float*)d_in[6];
    const float* b3 = (const float*)d_in[7];

    float* out_anchor = (float*)d_out;
    float* out_feat = out_anchor + (size_t)BB * TT * MM * 3;

    char* ws = (char*)d_ws;
    int* fps_idx = (int*)ws;                                   // 64 KB
    int* idxk = (int*)(ws + 65536);                            // 2 MB
    _Float16* Pp = (_Float16*)(ws + 65536 + 2097152);          // B*T*N*128 fp16 = 16 MB
    float* Qp = (float*)(ws + 65536 + 2097152 + 16777216);     // B*T*M*128 fp32 = 8 MB
    if (ws_size < (size_t)(65536 + 2097152 + 16777216) + (size_t)BB * TT * MM * 128 * 4)
        return;

    (void)hipFuncSetAttribute((const void*)k_fps, hipFuncAttributeMaxDynamicSharedMemorySize, FPS_LDS);
    k_fps<<<BB * TT / 4, 1024, FPS_LDS, stream>>>(xyzs, fps_idx);
    k_pp<<<BB * TT * NN / 64, 256, 0, stream>>>(xyzs, feats, w1, Pp);
    k_qp<<<BB * TT * MM / 64, 256, 0, stream>>>(xyzs, feats, w1, b1, fps_idx, Qp, out_anchor);
    k_knn<<<BB * TT * 64, 256, 0, stream>>>(xyzs, out_anchor, idxk);

    (void)hipFuncSetAttribute((const void*)k_mlp, hipFuncAttributeMaxDynamicSharedMemorySize, SM_TOTAL);
    k_mlp<<<256, 512, SM_TOTAL, stream>>>(Pp, Qp, idxk, w2, b2, w3, b3, out_feat);
}

// Round 11
// 543.055 us; speedup vs baseline: 1.5417x; 1.5417x over previous
//
#include <hip/hip_runtime.h>

// Problem constants (B=4, T=8, N=2048, C=64)
#define BB 4
#define TT 8
#define NN 2048
#define CC 64
#define MM 512           // N / SPATIAL_STRIDE
#define KK 32
#define H3DIM 256
#define RAD2 0.25f
#define FINF 3.4e38f

typedef _Float16 f16x8 __attribute__((ext_vector_type(8)));
typedef _Float16 f16x4 __attribute__((ext_vector_type(4)));
typedef float f32x4 __attribute__((ext_vector_type(4)));

// ---------------------------------------------------------------------------
// f32 DPP wave-64 max tree (row_shr 1/2/4/8 + row_bcast15/31, result lane 63).
// HW-validated rounds 2-9.
// ---------------------------------------------------------------------------
template <int CTRL>
__device__ __forceinline__ float dpp_max_step(float x) {
    int xi = __builtin_bit_cast(int, x);
    int yi = __builtin_amdgcn_update_dpp(xi, xi, CTRL, 0xf, 0xf, false);
    return fmaxf(x, __builtin_bit_cast(float, yi));
}
__device__ __forceinline__ float wave_max64(float x) {
    x = dpp_max_step<0x111>(x);
    x = dpp_max_step<0x112>(x);
    x = dpp_max_step<0x114>(x);
    x = dpp_max_step<0x118>(x);
    x = dpp_max_step<0x142>(x);
    x = dpp_max_step<0x143>(x);
    return __builtin_bit_cast(float, __builtin_amdgcn_readlane(__builtin_bit_cast(int, x), 63));
}
// Packed u64 DPP min (validated rounds 8/9 in k_knn).
template <int CTRL>
__device__ __forceinline__ unsigned long long dpp_minkey_step(unsigned long long k) {
    int lo = (int)(unsigned)k;
    int hi = (int)(unsigned)(k >> 32);
    int slo = __builtin_amdgcn_update_dpp(lo, lo, CTRL, 0xf, 0xf, false);
    int shi = __builtin_amdgcn_update_dpp(hi, hi, CTRL, 0xf, 0xf, false);
    unsigned long long s = ((unsigned long long)(unsigned)shi << 32) | (unsigned)slo;
    return s < k ? s : k;
}
__device__ __forceinline__ unsigned long long wave_minkey(unsigned long long k) {
    k = dpp_minkey_step<0x111>(k);
    k = dpp_minkey_step<0x112>(k);
    k = dpp_minkey_step<0x114>(k);
    k = dpp_minkey_step<0x118>(k);
    k = dpp_minkey_step<0x142>(k);
    k = dpp_minkey_step<0x143>(k);
    int lo = __builtin_amdgcn_readlane((int)(unsigned)k, 63);
    int hi = __builtin_amdgcn_readlane((int)(unsigned)(k >> 32), 63);
    return ((unsigned long long)(unsigned)hi << 32) | (unsigned)lo;
}

// ---------------------------------------------------------------------------
// Fused kernel 1: FPS (blocks 0..31, round-5 structure verbatim = 233 us) and
// P' (blocks 32..1055, round-9 k_pp verbatim). fps uses 32 CUs at ~2% VALU;
// pp's 1024 blocks run CONCURRENTLY on the remaining CUs (one-stream launches
// would serialize; fusion is the only overlap path under graph capture).
// Dynamic LDS pool carved per branch.
// ---------------------------------------------------------------------------
#define FPP_LDS 52224   // max(fps: 24640, pp: 68*128*4 + 64*68*4 = 52224)

__global__ __launch_bounds__(256) void k_fps_pp(const float* __restrict__ xyzs,
                                                const float* __restrict__ feats,
                                                const float* __restrict__ w1,
                                                int* __restrict__ fps_idx,
                                                _Float16* __restrict__ Pp) {
    extern __shared__ char fsm[];
    int tid = threadIdx.x;

    if (blockIdx.x < BB * TT) {
        // ------------------------- FPS branch (round-5 verbatim) -----------
        float* sx = (float*)fsm;
        float* sy = sx + NN;
        float* sz = sy + NN;
        float* pd = sz + NN;            // [2][4]
        int* pi = (int*)(pd + 8);       // [2][4]
        int bt = blockIdx.x;
        int lane = tid & 63, w = tid >> 6;
        const float* src = xyzs + (size_t)bt * NN * 3;
        for (int i = tid; i < NN; i += 256) {
            sx[i] = src[i * 3 + 0];
            sy[i] = src[i * 3 + 1];
            sz[i] = src[i * 3 + 2];
        }
        __syncthreads();

        float px[8], py[8], pz[8], dist[8];
#pragma unroll
        for (int j = 0; j < 8; ++j) {
            int p = tid * 8 + j;
            px[j] = sx[p]; py[j] = sy[p]; pz[j] = sz[p];
            dist[j] = 1e10f;
        }

        int cur = 0;
        if (tid == 0) fps_idx[bt * MM + 0] = 0;
        int pbase = tid * 8;

        for (int it = 1; it < MM; ++it) {
            float cx = sx[cur], cy = sy[cur], cz = sz[cur];   // broadcast reads
            float bestd = -1.0f;
            int bestp = 0;
#pragma unroll
            for (int j = 0; j < 8; ++j) {
                float dx = px[j] - cx, dy = py[j] - cy, dz = pz[j] - cz;
                float d = dx * dx + dy * dy + dz * dz;
                float nd = fminf(dist[j], d);
                dist[j] = nd;
                if (nd > bestd) { bestd = nd; bestp = pbase + j; }  // strict > keeps smallest j
            }
            float wmax = wave_max64(bestd);
            unsigned long long mask = __ballot(bestd == wmax);
            int wl = __ffsll(mask) - 1;
            int wbp = __builtin_amdgcn_readlane(bestp, wl);
            if (lane == 0) { pd[(it & 1) * 4 + w] = wmax; pi[(it & 1) * 4 + w] = wbp; }
            __syncthreads();
            float bd = pd[(it & 1) * 4 + 0];
            int bp = pi[(it & 1) * 4 + 0];
#pragma unroll
            for (int q = 1; q < 4; ++q) {
                float d2 = pd[(it & 1) * 4 + q];
                int p2 = pi[(it & 1) * 4 + q];
                if (d2 > bd) { bd = d2; bp = p2; }   // strict > : earlier wave wins ties
            }
            cur = bp;
            if (tid == 0) fps_idx[bt * MM + it] = cur;
        }
    } else {
        // ------------------------- P' branch (round-9 k_pp verbatim) -------
        float* sw = (float*)fsm;              // 68*128
        float* sin_ = sw + 68 * 128;          // 64*68
        for (int i = tid; i < 68 * 128; i += 256) {
            int r = i >> 7, c = i & 127;
            float v = 0.f;
            if (r < 64) v = w1[r * 128 + c];
            else if (r < 67) v = w1[(128 + r - 64) * 128 + c];
            sw[i] = v;
        }
        int row0 = (blockIdx.x - BB * TT) * 64;
        int bt = row0 >> 11;
        int b = bt >> 3, t = bt & 7;
        int tn = (t + 1 < TT) ? (t + 1) : (TT - 1);
        size_t nbase = (size_t)(b * TT + tn) * NN + (row0 & (NN - 1));
        const float* fsrc = feats + nbase * CC;
        const float* xsrc = xyzs + nbase * 3;
        for (int i = tid; i < 1024; i += 256) {
            float4 v = ((const float4*)fsrc)[i];
            int r = i >> 4, c = (i & 15) * 4;
            *(float4*)&sin_[r * 68 + c] = v;
        }
        if (tid < 192) {
            int r = tid / 3, c = tid - r * 3;
            sin_[r * 68 + 64 + c] = xsrc[tid];
        }
        if (tid < 64) sin_[tid * 68 + 67] = 0.f;
        __syncthreads();

        int rowg = tid >> 5, colg = tid & 31;
        float4 acc[8];
#pragma unroll
        for (int i = 0; i < 8; ++i) acc[i] = make_float4(0.f, 0.f, 0.f, 0.f);
        for (int k = 0; k < 68; k += 4) {
            float4 a4[8], b4[4];
#pragma unroll
            for (int i = 0; i < 8; ++i) a4[i] = *(const float4*)&sin_[(rowg * 8 + i) * 68 + k];
#pragma unroll
            for (int kk = 0; kk < 4; ++kk) b4[kk] = *(const float4*)&sw[(k + kk) * 128 + colg * 4];
#pragma unroll
            for (int i = 0; i < 8; ++i) {
#pragma unroll
                for (int kk = 0; kk < 4; ++kk) {
                    float av = (kk == 0) ? a4[i].x : (kk == 1) ? a4[i].y : (kk == 2) ? a4[i].z : a4[i].w;
                    acc[i].x += av * b4[kk].x;
                    acc[i].y += av * b4[kk].y;
                    acc[i].z += av * b4[kk].z;
                    acc[i].w += av * b4[kk].w;
                }
            }
        }
#pragma unroll
        for (int i = 0; i < 8; ++i) {
            f16x4 h;
            h[0] = (_Float16)acc[i].x; h[1] = (_Float16)acc[i].y;
            h[2] = (_Float16)acc[i].z; h[3] = (_Float16)acc[i].w;
            *(f16x4*)&Pp[(size_t)(row0 + rowg * 8 + i) * 128 + colg * 4] = h;
        }
    }
}

// ---------------------------------------------------------------------------
// Kernel 2b: Q' + anchors. (unchanged — verified)
// ---------------------------------------------------------------------------
__global__ __launch_bounds__(256) void k_qp(const float* __restrict__ xyzs,
                                            const float* __restrict__ feats,
                                            const float* __restrict__ w1,
                                            const float* __restrict__ b1,
                                            const int* __restrict__ fps_idx,
                                            float* __restrict__ Qp,
                                            float* __restrict__ out_anchor) {
    __shared__ float sw[68 * 128];
    __shared__ float sin_[64 * 68];
    __shared__ float sb[128];
    int tid = threadIdx.x;
    for (int i = tid; i < 68 * 128; i += 256) {
        int r = i >> 7, c = i & 127;
        float v = 0.f;
        if (r < 64) v = w1[(64 + r) * 128 + c];
        else if (r < 67) v = w1[(128 + r - 64) * 128 + c];
        sw[i] = v;
    }
    if (tid < 128) sb[tid] = b1[tid];
    int row0 = blockIdx.x * 64;
    int bt = row0 >> 9;
    size_t fbase = (size_t)bt * NN;
    {
        int r = tid >> 2, seg = tid & 3;
        int aidx = fps_idx[row0 + r];
        const float4* fr = (const float4*)(feats + (fbase + aidx) * CC);
#pragma unroll
        for (int i = 0; i < 4; ++i) {
            float4 v = fr[seg * 4 + i];
            *(float4*)&sin_[r * 68 + seg * 16 + i * 4] = v;
        }
    }
    if (tid < 64) {
        int aidx = fps_idx[row0 + tid];
        const float* xs = xyzs + (fbase + aidx) * 3;
        float x = xs[0], y = xs[1], z = xs[2];
        sin_[tid * 68 + 64] = -x;
        sin_[tid * 68 + 65] = -y;
        sin_[tid * 68 + 66] = -z;
        sin_[tid * 68 + 67] = 0.f;
        out_anchor[(size_t)(row0 + tid) * 3 + 0] = x;
        out_anchor[(size_t)(row0 + tid) * 3 + 1] = y;
        out_anchor[(size_t)(row0 + tid) * 3 + 2] = z;
    }
    __syncthreads();

    int rowg = tid >> 5, colg = tid & 31;
    float4 bias = *(const float4*)&sb[colg * 4];
    float4 acc[8];
#pragma unroll
    for (int i = 0; i < 8; ++i) acc[i] = bias;
    for (int k = 0; k < 68; k += 4) {
        float4 a4[8], b4[4];
#pragma unroll
        for (int i = 0; i < 8; ++i) a4[i] = *(const float4*)&sin_[(rowg * 8 + i) * 68 + k];
#pragma unroll
        for (int kk = 0; kk < 4; ++kk) b4[kk] = *(const float4*)&sw[(k + kk) * 128 + colg * 4];
#pragma unroll
        for (int i = 0; i < 8; ++i) {
#pragma unroll
            for (int kk = 0; kk < 4; ++kk) {
                float av = (kk == 0) ? a4[i].x : (kk == 1) ? a4[i].y : (kk == 2) ? a4[i].z : a4[i].w;
                acc[i].x += av * b4[kk].x;
                acc[i].y += av * b4[kk].y;
                acc[i].z += av * b4[kk].z;
                acc[i].w += av * b4[kk].w;
            }
        }
    }
#pragma unroll
    for (int i = 0; i < 8; ++i)
        *(float4*)&Qp[(size_t)(row0 + rowg * 8 + i) * 128 + colg * 4] = acc[i];
}

// ---------------------------------------------------------------------------
// Kernel 3: exact stable top-K=32 nearest + radius filter.
// Self-anchored: reads fps_idx + xyzs directly (bit-identical to qp's anchor
// values) so it no longer depends on k_qp. Core unchanged from rounds 8/9.
// ---------------------------------------------------------------------------
__global__ __launch_bounds__(256) void k_knn(const float* __restrict__ xyzs,
                                             const int* __restrict__ fps_idx,
                                             int* __restrict__ idxk) {
    __shared__ float sx[NN], sy[NN], sz[NN];
    int tid = threadIdx.x;
    int wave = tid >> 6, lane = tid & 63;
    int bt = blockIdx.x >> 6;              // 64 blocks per (b,t)
    int sub = blockIdx.x & 63;
    int b = bt >> 3, t = bt & 7;
    int tn = (t + 1 < TT) ? (t + 1) : (TT - 1);
    const float* src = xyzs + ((size_t)(b * TT + tn)) * NN * 3;
    for (int i = tid; i < NN; i += 256) {
        sx[i] = src[i * 3 + 0];
        sy[i] = src[i * 3 + 1];
        sz[i] = src[i * 3 + 2];
    }
    __syncthreads();

    for (int a = 0; a < 2; ++a) {
        int mrow = bt * MM + sub * 8 + wave * 2 + a;
        int aidx = fps_idx[mrow];
        const float* xs = xyzs + ((size_t)bt * NN + aidx) * 3;   // frame t itself
        float ax = xs[0], ay = xs[1], az = xs[2];
        float d[32];
#pragma unroll
        for (int j = 0; j < 32; ++j) {
            int p = j * 64 + lane;
            float dx = sx[p] - ax, dy = sy[p] - ay, dz = sz[p] - az;
            d[j] = dx * dx + dy * dy + dz * dz;
        }
        int p0 = 0;
        int myidx = 0;
        for (int r = 0; r < KK; ++r) {
            float gd[4];
            int gp[4];
#pragma unroll
            for (int g = 0; g < 4; ++g) {
                gd[g] = d[g * 8];
                gp[g] = (g * 8) * 64 + lane;
#pragma unroll
                for (int jj = 1; jj < 8; ++jj) {
                    float dj = d[g * 8 + jj];
                    if (dj < gd[g]) { gd[g] = dj; gp[g] = (g * 8 + jj) * 64 + lane; }  // strict <
                }
            }
            bool u01 = gd[1] < gd[0], u23 = gd[3] < gd[2];
            float da = u01 ? gd[1] : gd[0], db = u23 ? gd[3] : gd[2];
            int pa = u01 ? gp[1] : gp[0], pb = u23 ? gp[3] : gp[2];
            bool uf = db < da;
            float bd = uf ? db : da;
            int bp = uf ? pb : pa;
            unsigned long long key =
                ((unsigned long long)(unsigned)__builtin_bit_cast(unsigned, bd) << 32) |
                (unsigned)bp;
            unsigned long long wkey = wave_minkey(key);
            int pstar = (int)(unsigned)wkey;
            float dstar = __builtin_bit_cast(float, (unsigned)(wkey >> 32));
            if (r == 0) { p0 = pstar; myidx = pstar; }
            int outp = (dstar <= RAD2) ? pstar : p0;   // radius replacement
            if (lane == r) myidx = outp;
            if (r < KK - 1) {
                int lanew = pstar & 63;                 // uniform (SGPR)
                int jw = pstar >> 6;                    // uniform (SGPR)
                bool imw = (lane == lanew);
#pragma unroll
                for (int j = 0; j < 32; ++j)
                    d[j] = (imw && j == jw) ? FINF : d[j];
            }
        }
        if (lane < KK) idxk[(size_t)mrow * KK + lane] = myidx;
    }
}

// ---------------------------------------------------------------------------
// Kernel 4: persistent-block fp16 MFMA MLP (layers 2+3) + max over K.
// (unchanged — verified; 512 thr / 8 waves)
// ---------------------------------------------------------------------------
#define SM_W2 0
#define SM_W3 32768
#define SM_H1 98304
#define SM_H2 114688
#define SM_B2 131072
#define SM_B3 131584
#define SM_TOTAL 132608

__global__ __launch_bounds__(512, 1) void k_mlp(const _Float16* __restrict__ Pp,
                                                const float* __restrict__ Qp,
                                                const int* __restrict__ idxk,
                                                const float* __restrict__ w2,
                                                const float* __restrict__ b2,
                                                const float* __restrict__ w3,
                                                const float* __restrict__ b3,
                                                float* __restrict__ out_feat) {
    extern __shared__ char smem[];
    int tid = threadIdx.x;
    int bid = blockIdx.x;                  // 0..255

    for (int i = tid; i < 128 * 128; i += 512) {
        int n = i & 127, kk = i >> 7;
        _Float16 v = (_Float16)w2[kk * 128 + n];
        *(_Float16*)(smem + SM_W2 + n * 256 + ((2 * kk) ^ ((n & 7) << 4))) = v;
    }
    for (int i = tid; i < 256 * 128; i += 512) {
        int n = i & 255, kk = i >> 8;
        _Float16 v = (_Float16)w3[kk * 256 + n];
        *(_Float16*)(smem + SM_W3 + n * 256 + ((2 * kk) ^ ((n & 7) << 4))) = v;
    }
    if (tid < 128) *(float*)(smem + SM_B2 + tid * 4) = b2[tid];
    if (tid < 256) *(float*)(smem + SM_B3 + tid * 4) = b3[tid];
    __syncthreads();

    int lane = tid & 63;
    int w = tid >> 6;                      // 0..7
    int wm = w >> 2, wn = w & 3;           // 2 anchors x 4 col-groups
    int l15 = lane & 15, g = lane >> 4;
    int hswz = (l15 & 7) << 4;

    const f32x4 zero4 = {0.f, 0.f, 0.f, 0.f};

    for (int c = 0; c < 32; ++c) {
        int a0 = bid * 64 + c * 2;
        int bt = a0 >> 9;

        {
            int r = tid >> 3, seg = tid & 7;
            int arow = a0 + (r >> 5);
            int kidx = r & 31;
            int nk = idxk[(size_t)arow * KK + kidx];
            const _Float16* ps = Pp + ((size_t)(bt * NN + nk)) * 128 + seg * 16;
            const float* qs = Qp + (size_t)arow * 128 + seg * 16;
            int rowbase = SM_H1 + r * 256;
            int swz = (r & 7) << 4;
#pragma unroll
            for (int i = 0; i < 2; ++i) {
                f16x8 pv = *(const f16x8*)(ps + i * 8);
                f32x4 q0 = *(const f32x4*)(qs + i * 8);
                f32x4 q1 = *(const f32x4*)(qs + i * 8 + 4);
                f16x8 hv;
#pragma unroll
                for (int j = 0; j < 4; ++j) hv[j] = (_Float16)fmaxf((float)pv[j] + q0[j], 0.f);
#pragma unroll
                for (int j = 0; j < 4; ++j) hv[4 + j] = (_Float16)fmaxf((float)pv[4 + j] + q1[j], 0.f);
                *(f16x8*)(smem + rowbase + ((seg * 32 + i * 16) ^ swz)) = hv;
            }
        }
        __syncthreads();

        f32x4 acc2[2][2];
#pragma unroll
        for (int m = 0; m < 2; ++m)
#pragma unroll
            for (int n = 0; n < 2; ++n) acc2[m][n] = zero4;

#pragma unroll
        for (int ks = 0; ks < 4; ++ks) {
            int kbyte = ks * 64 + g * 16;
            f16x8 af[2], bf[2];
#pragma unroll
            for (int m = 0; m < 2; ++m) {
                int row = wm * 32 + m * 16 + l15;
                af[m] = *(const f16x8*)(smem + SM_H1 + row * 256 + (kbyte ^ hswz));
            }
#pragma unroll
            for (int n = 0; n < 2; ++n) {
                int col = wn * 32 + n * 16 + l15;
                bf[n] = *(const f16x8*)(smem + SM_W2 + col * 256 + (kbyte ^ hswz));
            }
#pragma unroll
            for (int m = 0; m < 2; ++m)
#pragma unroll
                for (int n = 0; n < 2; ++n)
                    acc2[m][n] = __builtin_amdgcn_mfma_f32_16x16x32_f16(af[m], bf[n], acc2[m][n], 0, 0, 0);
        }
#pragma unroll
        for (int m = 0; m < 2; ++m)
#pragma unroll
            for (int n = 0; n < 2; ++n) {
                int col = wn * 32 + n * 16 + l15;
                float bb = *(const float*)(smem + SM_B2 + col * 4);
#pragma unroll
                for (int r = 0; r < 4; ++r) {
                    int row = wm * 32 + m * 16 + g * 4 + r;
                    float v = fmaxf(acc2[m][n][r] + bb, 0.f);
                    *(_Float16*)(smem + SM_H2 + row * 256 + ((2 * col) ^ ((row & 7) << 4))) = (_Float16)v;
                }
            }
        __syncthreads();

        f32x4 acc3[2][4];
#pragma unroll
        for (int m = 0; m < 2; ++m)
#pragma unroll
            for (int n = 0; n < 4; ++n) acc3[m][n] = zero4;

#pragma unroll
        for (int ks = 0; ks < 4; ++ks) {
            int kbyte = ks * 64 + g * 16;
            f16x8 af[2], bf[4];
#pragma unroll
            for (int m = 0; m < 2; ++m) {
                int row = wm * 32 + m * 16 + l15;
                af[m] = *(const f16x8*)(smem + SM_H2 + row * 256 + (kbyte ^ hswz));
            }
#pragma unroll
            for (int n = 0; n < 4; ++n) {
                int col = wn * 64 + n * 16 + l15;
                bf[n] = *(const f16x8*)(smem + SM_W3 + col * 256 + (kbyte ^ hswz));
            }
#pragma unroll
            for (int m = 0; m < 2; ++m)
#pragma unroll
                for (int n = 0; n < 4; ++n)
                    acc3[m][n] = __builtin_amdgcn_mfma_f32_16x16x32_f16(af[m], bf[n], acc3[m][n], 0, 0, 0);
        }
#pragma unroll
        for (int n = 0; n < 4; ++n) {
            int col = wn * 64 + n * 16 + l15;
            float s = acc3[0][n][0];
#pragma unroll
            for (int r = 1; r < 4; ++r) s = fmaxf(s, acc3[0][n][r]);
#pragma unroll
            for (int r = 0; r < 4; ++r) s = fmaxf(s, acc3[1][n][r]);
            s = fmaxf(s, __shfl_xor(s, 16));
            s = fmaxf(s, __shfl_xor(s, 32));
            if (g == 0) {
                float bb = *(const float*)(smem + SM_B3 + col * 4);
                out_feat[(size_t)(a0 + wm) * H3DIM + col] = fmaxf(s + bb, 0.f);
            }
        }
        __syncthreads();
    }
}

// ---------------------------------------------------------------------------
extern "C" void kernel_launch(void* const* d_in, const int* in_sizes, int n_in,
                              void* d_out, int out_size, void* d_ws, size_t ws_size,
                              hipStream_t stream) {
    const float* xyzs  = (const float*)d_in[0];
    const float* feats = (const float*)d_in[1];
    const float* w1 = (const float*)d_in[2];
    const float* b1 = (const float*)d_in[3];
    const float* w2 = (const float*)d_in[4];
    const float* b2 = (const float*)d_in[5];
    const float* w3 = (const float*)d_in[6];
    const float* b3 = (const float*)d_in[7];

    float* out_anchor = (float*)d_out;
    float* out_feat = out_anchor + (size_t)BB * TT * MM * 3;

    char* ws = (char*)d_ws;
    int* fps_idx = (int*)ws;                                   // 64 KB
    int* idxk = (int*)(ws + 65536);                            // 2 MB
    _Float16* Pp = (_Float16*)(ws + 65536 + 2097152);          // B*T*N*128 fp16 = 16 MB
    float* Qp = (float*)(ws + 65536 + 2097152 + 16777216);     // B*T*M*128 fp32 = 8 MB
    if (ws_size < (size_t)(65536 + 2097152 + 16777216) + (size_t)BB * TT * MM * 128 * 4)
        return;

    (void)hipFuncSetAttribute((const void*)k_fps_pp, hipFuncAttributeMaxDynamicSharedMemorySize, FPP_LDS);
    k_fps_pp<<<BB * TT + BB * TT * NN / 64, 256, FPP_LDS, stream>>>(xyzs, feats, w1, fps_idx, Pp);
    k_knn<<<BB * TT * 64, 256, 0, stream>>>(xyzs, fps_idx, idxk);
    k_qp<<<BB * TT * MM / 64, 256, 0, stream>>>(xyzs, feats, w1, b1, fps_idx, Qp, out_anchor);

    (void)hipFuncSetAttribute((const void*)k_mlp, hipFuncAttributeMaxDynamicSharedMemorySize, SM_TOTAL);
    k_mlp<<<256, 512, SM_TOTAL, stream>>>(Pp, Qp, idxk, w2, b2, w3, b3, out_feat);
}

// Round 12
// 541.902 us; speedup vs baseline: 1.5449x; 1.0021x over previous
//
#include <hip/hip_runtime.h>

// Problem constants (B=4, T=8, N=2048, C=64)
#define BB 4
#define TT 8
#define NN 2048
#define CC 64
#define MM 512           // N / SPATIAL_STRIDE
#define KK 32
#define H3DIM 256
#define RAD2 0.25f
#define FINF 3.4e38f

typedef _Float16 f16x8 __attribute__((ext_vector_type(8)));
typedef _Float16 f16x4 __attribute__((ext_vector_type(4)));
typedef float f32x4 __attribute__((ext_vector_type(4)));

// ---------------------------------------------------------------------------
// f32 DPP wave-64 max tree (row_shr 1/2/4/8 + row_bcast15/31, result lane 63).
// HW-validated rounds 2-11.
// ---------------------------------------------------------------------------
template <int CTRL>
__device__ __forceinline__ float dpp_max_step(float x) {
    int xi = __builtin_bit_cast(int, x);
    int yi = __builtin_amdgcn_update_dpp(xi, xi, CTRL, 0xf, 0xf, false);
    return fmaxf(x, __builtin_bit_cast(float, yi));
}
__device__ __forceinline__ float wave_max64(float x) {
    x = dpp_max_step<0x111>(x);
    x = dpp_max_step<0x112>(x);
    x = dpp_max_step<0x114>(x);
    x = dpp_max_step<0x118>(x);
    x = dpp_max_step<0x142>(x);
    x = dpp_max_step<0x143>(x);
    return __builtin_bit_cast(float, __builtin_amdgcn_readlane(__builtin_bit_cast(int, x), 63));
}
// Packed u64 DPP min (validated rounds 8-11 in k_knn).
template <int CTRL>
__device__ __forceinline__ unsigned long long dpp_minkey_step(unsigned long long k) {
    int lo = (int)(unsigned)k;
    int hi = (int)(unsigned)(k >> 32);
    int slo = __builtin_amdgcn_update_dpp(lo, lo, CTRL, 0xf, 0xf, false);
    int shi = __builtin_amdgcn_update_dpp(hi, hi, CTRL, 0xf, 0xf, false);
    unsigned long long s = ((unsigned long long)(unsigned)shi << 32) | (unsigned)slo;
    return s < k ? s : k;
}
__device__ __forceinline__ unsigned long long wave_minkey(unsigned long long k) {
    k = dpp_minkey_step<0x111>(k);
    k = dpp_minkey_step<0x112>(k);
    k = dpp_minkey_step<0x114>(k);
    k = dpp_minkey_step<0x118>(k);
    k = dpp_minkey_step<0x142>(k);
    k = dpp_minkey_step<0x143>(k);
    int lo = __builtin_amdgcn_readlane((int)(unsigned)k, 63);
    int hi = __builtin_amdgcn_readlane((int)(unsigned)(k >> 32), 63);
    return ((unsigned long long)(unsigned)hi << 32) | (unsigned)lo;
}

// ---------------------------------------------------------------------------
// Fused kernel 1: FPS (blocks 0..31) + P' (blocks 32..1055).
// (unchanged from round 11 — verified, 245 us)
// ---------------------------------------------------------------------------
#define FPP_LDS 52224   // max(fps: 24640, pp: 68*128*4 + 64*68*4 = 52224)

__global__ __launch_bounds__(256) void k_fps_pp(const float* __restrict__ xyzs,
                                                const float* __restrict__ feats,
                                                const float* __restrict__ w1,
                                                int* __restrict__ fps_idx,
                                                _Float16* __restrict__ Pp) {
    extern __shared__ char fsm[];
    int tid = threadIdx.x;

    if (blockIdx.x < BB * TT) {
        // ------------------------- FPS branch (round-5 verbatim) -----------
        float* sx = (float*)fsm;
        float* sy = sx + NN;
        float* sz = sy + NN;
        float* pd = sz + NN;            // [2][4]
        int* pi = (int*)(pd + 8);       // [2][4]
        int bt = blockIdx.x;
        int lane = tid & 63, w = tid >> 6;
        const float* src = xyzs + (size_t)bt * NN * 3;
        for (int i = tid; i < NN; i += 256) {
            sx[i] = src[i * 3 + 0];
            sy[i] = src[i * 3 + 1];
            sz[i] = src[i * 3 + 2];
        }
        __syncthreads();

        float px[8], py[8], pz[8], dist[8];
#pragma unroll
        for (int j = 0; j < 8; ++j) {
            int p = tid * 8 + j;
            px[j] = sx[p]; py[j] = sy[p]; pz[j] = sz[p];
            dist[j] = 1e10f;
        }

        int cur = 0;
        if (tid == 0) fps_idx[bt * MM + 0] = 0;
        int pbase = tid * 8;

        for (int it = 1; it < MM; ++it) {
            float cx = sx[cur], cy = sy[cur], cz = sz[cur];   // broadcast reads
            float bestd = -1.0f;
            int bestp = 0;
#pragma unroll
            for (int j = 0; j < 8; ++j) {
                float dx = px[j] - cx, dy = py[j] - cy, dz = pz[j] - cz;
                float d = dx * dx + dy * dy + dz * dz;
                float nd = fminf(dist[j], d);
                dist[j] = nd;
                if (nd > bestd) { bestd = nd; bestp = pbase + j; }  // strict > keeps smallest j
            }
            float wmax = wave_max64(bestd);
            unsigned long long mask = __ballot(bestd == wmax);
            int wl = __ffsll(mask) - 1;
            int wbp = __builtin_amdgcn_readlane(bestp, wl);
            if (lane == 0) { pd[(it & 1) * 4 + w] = wmax; pi[(it & 1) * 4 + w] = wbp; }
            __syncthreads();
            float bd = pd[(it & 1) * 4 + 0];
            int bp = pi[(it & 1) * 4 + 0];
#pragma unroll
            for (int q = 1; q < 4; ++q) {
                float d2 = pd[(it & 1) * 4 + q];
                int p2 = pi[(it & 1) * 4 + q];
                if (d2 > bd) { bd = d2; bp = p2; }   // strict > : earlier wave wins ties
            }
            cur = bp;
            if (tid == 0) fps_idx[bt * MM + it] = cur;
        }
    } else {
        // ------------------------- P' branch (round-9 k_pp verbatim) -------
        float* sw = (float*)fsm;              // 68*128
        float* sin_ = sw + 68 * 128;          // 64*68
        for (int i = tid; i < 68 * 128; i += 256) {
            int r = i >> 7, c = i & 127;
            float v = 0.f;
            if (r < 64) v = w1[r * 128 + c];
            else if (r < 67) v = w1[(128 + r - 64) * 128 + c];
            sw[i] = v;
        }
        int row0 = (blockIdx.x - BB * TT) * 64;
        int bt = row0 >> 11;
        int b = bt >> 3, t = bt & 7;
        int tn = (t + 1 < TT) ? (t + 1) : (TT - 1);
        size_t nbase = (size_t)(b * TT + tn) * NN + (row0 & (NN - 1));
        const float* fsrc = feats + nbase * CC;
        const float* xsrc = xyzs + nbase * 3;
        for (int i = tid; i < 1024; i += 256) {
            float4 v = ((const float4*)fsrc)[i];
            int r = i >> 4, c = (i & 15) * 4;
            *(float4*)&sin_[r * 68 + c] = v;
        }
        if (tid < 192) {
            int r = tid / 3, c = tid - r * 3;
            sin_[r * 68 + 64 + c] = xsrc[tid];
        }
        if (tid < 64) sin_[tid * 68 + 67] = 0.f;
        __syncthreads();

        int rowg = tid >> 5, colg = tid & 31;
        float4 acc[8];
#pragma unroll
        for (int i = 0; i < 8; ++i) acc[i] = make_float4(0.f, 0.f, 0.f, 0.f);
        for (int k = 0; k < 68; k += 4) {
            float4 a4[8], b4[4];
#pragma unroll
            for (int i = 0; i < 8; ++i) a4[i] = *(const float4*)&sin_[(rowg * 8 + i) * 68 + k];
#pragma unroll
            for (int kk = 0; kk < 4; ++kk) b4[kk] = *(const float4*)&sw[(k + kk) * 128 + colg * 4];
#pragma unroll
            for (int i = 0; i < 8; ++i) {
#pragma unroll
                for (int kk = 0; kk < 4; ++kk) {
                    float av = (kk == 0) ? a4[i].x : (kk == 1) ? a4[i].y : (kk == 2) ? a4[i].z : a4[i].w;
                    acc[i].x += av * b4[kk].x;
                    acc[i].y += av * b4[kk].y;
                    acc[i].z += av * b4[kk].z;
                    acc[i].w += av * b4[kk].w;
                }
            }
        }
#pragma unroll
        for (int i = 0; i < 8; ++i) {
            f16x4 h;
            h[0] = (_Float16)acc[i].x; h[1] = (_Float16)acc[i].y;
            h[2] = (_Float16)acc[i].z; h[3] = (_Float16)acc[i].w;
            *(f16x4*)&Pp[(size_t)(row0 + rowg * 8 + i) * 128 + colg * 4] = h;
        }
    }
}

// ---------------------------------------------------------------------------
// Kernel 2b: Q' + anchors. (unchanged — verified)
// ---------------------------------------------------------------------------
__global__ __launch_bounds__(256) void k_qp(const float* __restrict__ xyzs,
                                            const float* __restrict__ feats,
                                            const float* __restrict__ w1,
                                            const float* __restrict__ b1,
                                            const int* __restrict__ fps_idx,
                                            float* __restrict__ Qp,
                                            float* __restrict__ out_anchor) {
    __shared__ float sw[68 * 128];
    __shared__ float sin_[64 * 68];
    __shared__ float sb[128];
    int tid = threadIdx.x;
    for (int i = tid; i < 68 * 128; i += 256) {
        int r = i >> 7, c = i & 127;
        float v = 0.f;
        if (r < 64) v = w1[(64 + r) * 128 + c];
        else if (r < 67) v = w1[(128 + r - 64) * 128 + c];
        sw[i] = v;
    }
    if (tid < 128) sb[tid] = b1[tid];
    int row0 = blockIdx.x * 64;
    int bt = row0 >> 9;
    size_t fbase = (size_t)bt * NN;
    {
        int r = tid >> 2, seg = tid & 3;
        int aidx = fps_idx[row0 + r];
        const float4* fr = (const float4*)(feats + (fbase + aidx) * CC);
#pragma unroll
        for (int i = 0; i < 4; ++i) {
            float4 v = fr[seg * 4 + i];
            *(float4*)&sin_[r * 68 + seg * 16 + i * 4] = v;
        }
    }
    if (tid < 64) {
        int aidx = fps_idx[row0 + tid];
        const float* xs = xyzs + (fbase + aidx) * 3;
        float x = xs[0], y = xs[1], z = xs[2];
        sin_[tid * 68 + 64] = -x;
        sin_[tid * 68 + 65] = -y;
        sin_[tid * 68 + 66] = -z;
        sin_[tid * 68 + 67] = 0.f;
        out_anchor[(size_t)(row0 + tid) * 3 + 0] = x;
        out_anchor[(size_t)(row0 + tid) * 3 + 1] = y;
        out_anchor[(size_t)(row0 + tid) * 3 + 2] = z;
    }
    __syncthreads();

    int rowg = tid >> 5, colg = tid & 31;
    float4 bias = *(const float4*)&sb[colg * 4];
    float4 acc[8];
#pragma unroll
    for (int i = 0; i < 8; ++i) acc[i] = bias;
    for (int k = 0; k < 68; k += 4) {
        float4 a4[8], b4[4];
#pragma unroll
        for (int i = 0; i < 8; ++i) a4[i] = *(const float4*)&sin_[(rowg * 8 + i) * 68 + k];
#pragma unroll
        for (int kk = 0; kk < 4; ++kk) b4[kk] = *(const float4*)&sw[(k + kk) * 128 + colg * 4];
#pragma unroll
        for (int i = 0; i < 8; ++i) {
#pragma unroll
            for (int kk = 0; kk < 4; ++kk) {
                float av = (kk == 0) ? a4[i].x : (kk == 1) ? a4[i].y : (kk == 2) ? a4[i].z : a4[i].w;
                acc[i].x += av * b4[kk].x;
                acc[i].y += av * b4[kk].y;
                acc[i].z += av * b4[kk].z;
                acc[i].w += av * b4[kk].w;
            }
        }
    }
#pragma unroll
    for (int i = 0; i < 8; ++i)
        *(float4*)&Qp[(size_t)(row0 + rowg * 8 + i) * 128 + colg * 4] = acc[i];
}

// ---------------------------------------------------------------------------
// Kernel 3: exact stable top-K=32 nearest + radius filter.
// (unchanged from round 11 — verified; self-anchored via fps_idx)
// ---------------------------------------------------------------------------
__global__ __launch_bounds__(256) void k_knn(const float* __restrict__ xyzs,
                                             const int* __restrict__ fps_idx,
                                             int* __restrict__ idxk) {
    __shared__ float sx[NN], sy[NN], sz[NN];
    int tid = threadIdx.x;
    int wave = tid >> 6, lane = tid & 63;
    int bt = blockIdx.x >> 6;              // 64 blocks per (b,t)
    int sub = blockIdx.x & 63;
    int b = bt >> 3, t = bt & 7;
    int tn = (t + 1 < TT) ? (t + 1) : (TT - 1);
    const float* src = xyzs + ((size_t)(b * TT + tn)) * NN * 3;
    for (int i = tid; i < NN; i += 256) {
        sx[i] = src[i * 3 + 0];
        sy[i] = src[i * 3 + 1];
        sz[i] = src[i * 3 + 2];
    }
    __syncthreads();

    for (int a = 0; a < 2; ++a) {
        int mrow = bt * MM + sub * 8 + wave * 2 + a;
        int aidx = fps_idx[mrow];
        const float* xs = xyzs + ((size_t)bt * NN + aidx) * 3;   // frame t itself
        float ax = xs[0], ay = xs[1], az = xs[2];
        float d[32];
#pragma unroll
        for (int j = 0; j < 32; ++j) {
            int p = j * 64 + lane;
            float dx = sx[p] - ax, dy = sy[p] - ay, dz = sz[p] - az;
            d[j] = dx * dx + dy * dy + dz * dz;
        }
        int p0 = 0;
        int myidx = 0;
        for (int r = 0; r < KK; ++r) {
            float gd[4];
            int gp[4];
#pragma unroll
            for (int g = 0; g < 4; ++g) {
                gd[g] = d[g * 8];
                gp[g] = (g * 8) * 64 + lane;
#pragma unroll
                for (int jj = 1; jj < 8; ++jj) {
                    float dj = d[g * 8 + jj];
                    if (dj < gd[g]) { gd[g] = dj; gp[g] = (g * 8 + jj) * 64 + lane; }  // strict <
                }
            }
            bool u01 = gd[1] < gd[0], u23 = gd[3] < gd[2];
            float da = u01 ? gd[1] : gd[0], db = u23 ? gd[3] : gd[2];
            int pa = u01 ? gp[1] : gp[0], pb = u23 ? gp[3] : gp[2];
            bool uf = db < da;
            float bd = uf ? db : da;
            int bp = uf ? pb : pa;
            unsigned long long key =
                ((unsigned long long)(unsigned)__builtin_bit_cast(unsigned, bd) << 32) |
                (unsigned)bp;
            unsigned long long wkey = wave_minkey(key);
            int pstar = (int)(unsigned)wkey;
            float dstar = __builtin_bit_cast(float, (unsigned)(wkey >> 32));
            if (r == 0) { p0 = pstar; myidx = pstar; }
            int outp = (dstar <= RAD2) ? pstar : p0;   // radius replacement
            if (lane == r) myidx = outp;
            if (r < KK - 1) {
                int lanew = pstar & 63;                 // uniform (SGPR)
                int jw = pstar >> 6;                    // uniform (SGPR)
                bool imw = (lane == lanew);
#pragma unroll
                for (int j = 0; j < 32; ++j)
                    d[j] = (imw && j == jw) ? FINF : d[j];
            }
        }
        if (lane < KK) idxk[(size_t)mrow * KK + lane] = myidx;
    }
}

// ---------------------------------------------------------------------------
// Kernel 4: persistent-block fp16 MFMA MLP (layers 2+3) + max over K.
// NOW 1024 threads / 16 waves (4 waves/SIMD) — wave grid 2 anchors x 8
// col-groups. Same LDS layout/swizzle; per-output MFMA accumulation order
// unchanged (bitwise-identical results; only wave->output mapping changed).
// ---------------------------------------------------------------------------
#define SM_W2 0
#define SM_W3 32768
#define SM_H1 98304
#define SM_H2 114688
#define SM_B2 131072
#define SM_B3 131584
#define SM_TOTAL 132608

__global__ __launch_bounds__(1024, 1) void k_mlp(const _Float16* __restrict__ Pp,
                                                 const float* __restrict__ Qp,
                                                 const int* __restrict__ idxk,
                                                 const float* __restrict__ w2,
                                                 const float* __restrict__ b2,
                                                 const float* __restrict__ w3,
                                                 const float* __restrict__ b3,
                                                 float* __restrict__ out_feat) {
    extern __shared__ char smem[];
    int tid = threadIdx.x;
    int bid = blockIdx.x;                  // 0..255

    for (int i = tid; i < 128 * 128; i += 1024) {
        int n = i & 127, kk = i >> 7;
        _Float16 v = (_Float16)w2[kk * 128 + n];
        *(_Float16*)(smem + SM_W2 + n * 256 + ((2 * kk) ^ ((n & 7) << 4))) = v;
    }
    for (int i = tid; i < 256 * 128; i += 1024) {
        int n = i & 255, kk = i >> 8;
        _Float16 v = (_Float16)w3[kk * 256 + n];
        *(_Float16*)(smem + SM_W3 + n * 256 + ((2 * kk) ^ ((n & 7) << 4))) = v;
    }
    if (tid < 128) *(float*)(smem + SM_B2 + tid * 4) = b2[tid];
    if (tid < 256) *(float*)(smem + SM_B3 + tid * 4) = b3[tid];
    __syncthreads();

    int lane = tid & 63;
    int w = tid >> 6;                      // 0..15
    int wm = w >> 3, wn = w & 7;           // 2 anchors x 8 col-groups
    int l15 = lane & 15, g = lane >> 4;
    int hswz = (l15 & 7) << 4;

    const f32x4 zero4 = {0.f, 0.f, 0.f, 0.f};

    for (int c = 0; c < 32; ++c) {
        int a0 = bid * 64 + c * 2;
        int bt = a0 >> 9;

        // ---- build h1: 64 rows x 16 segments of 8 fp16, one f16x8/thread ----
        {
            int r = tid >> 4, seg = tid & 15;
            int arow = a0 + (r >> 5);
            int kidx = r & 31;
            int nk = idxk[(size_t)arow * KK + kidx];
            const _Float16* ps = Pp + ((size_t)(bt * NN + nk)) * 128 + seg * 8;
            const float* qs = Qp + (size_t)arow * 128 + seg * 8;
            int rowbase = SM_H1 + r * 256;
            int swz = (r & 7) << 4;
            f16x8 pv = *(const f16x8*)ps;
            f32x4 q0 = *(const f32x4*)qs;
            f32x4 q1 = *(const f32x4*)(qs + 4);
            f16x8 hv;
#pragma unroll
            for (int j = 0; j < 4; ++j) hv[j] = (_Float16)fmaxf((float)pv[j] + q0[j], 0.f);
#pragma unroll
            for (int j = 0; j < 4; ++j) hv[4 + j] = (_Float16)fmaxf((float)pv[4 + j] + q1[j], 0.f);
            *(f16x8*)(smem + rowbase + ((seg * 16) ^ swz)) = hv;
        }
        __syncthreads();

        // ---- layer 2: wave tile 32 rows x 16 cols ----
        f32x4 acc2[2];
#pragma unroll
        for (int m = 0; m < 2; ++m) acc2[m] = zero4;

#pragma unroll
        for (int ks = 0; ks < 4; ++ks) {
            int kbyte = ks * 64 + g * 16;
            f16x8 af[2], bf;
#pragma unroll
            for (int m = 0; m < 2; ++m) {
                int row = wm * 32 + m * 16 + l15;
                af[m] = *(const f16x8*)(smem + SM_H1 + row * 256 + (kbyte ^ hswz));
            }
            {
                int col = wn * 16 + l15;
                bf = *(const f16x8*)(smem + SM_W2 + col * 256 + (kbyte ^ hswz));
            }
#pragma unroll
            for (int m = 0; m < 2; ++m)
                acc2[m] = __builtin_amdgcn_mfma_f32_16x16x32_f16(af[m], bf, acc2[m], 0, 0, 0);
        }
#pragma unroll
        for (int m = 0; m < 2; ++m) {
            int col = wn * 16 + l15;
            float bb = *(const float*)(smem + SM_B2 + col * 4);
#pragma unroll
            for (int r = 0; r < 4; ++r) {
                int row = wm * 32 + m * 16 + g * 4 + r;
                float v = fmaxf(acc2[m][r] + bb, 0.f);
                *(_Float16*)(smem + SM_H2 + row * 256 + ((2 * col) ^ ((row & 7) << 4))) = (_Float16)v;
            }
        }
        __syncthreads();

        // ---- layer 3: wave tile 32 rows x 32 cols; max over K fused ----
        f32x4 acc3[2][2];
#pragma unroll
        for (int m = 0; m < 2; ++m)
#pragma unroll
            for (int n = 0; n < 2; ++n) acc3[m][n] = zero4;

#pragma unroll
        for (int ks = 0; ks < 4; ++ks) {
            int kbyte = ks * 64 + g * 16;
            f16x8 af[2], bf[2];
#pragma unroll
            for (int m = 0; m < 2; ++m) {
                int row = wm * 32 + m * 16 + l15;
                af[m] = *(const f16x8*)(smem + SM_H2 + row * 256 + (kbyte ^ hswz));
            }
#pragma unroll
            for (int n = 0; n < 2; ++n) {
                int col = wn * 32 + n * 16 + l15;
                bf[n] = *(const f16x8*)(smem + SM_W3 + col * 256 + (kbyte ^ hswz));
            }
#pragma unroll
            for (int m = 0; m < 2; ++m)
#pragma unroll
                for (int n = 0; n < 2; ++n)
                    acc3[m][n] = __builtin_amdgcn_mfma_f32_16x16x32_f16(af[m], bf[n], acc3[m][n], 0, 0, 0);
        }
#pragma unroll
        for (int n = 0; n < 2; ++n) {
            int col = wn * 32 + n * 16 + l15;
            float s = acc3[0][n][0];
#pragma unroll
            for (int r = 1; r < 4; ++r) s = fmaxf(s, acc3[0][n][r]);
#pragma unroll
            for (int r = 0; r < 4; ++r) s = fmaxf(s, acc3[1][n][r]);
            s = fmaxf(s, __shfl_xor(s, 16));
            s = fmaxf(s, __shfl_xor(s, 32));
            if (g == 0) {
                float bb = *(const float*)(smem + SM_B3 + col * 4);
                out_feat[(size_t)(a0 + wm) * H3DIM + col] = fmaxf(s + bb, 0.f);
            }
        }
        __syncthreads();
    }
}

// ---------------------------------------------------------------------------
extern "C" void kernel_launch(void* const* d_in, const int* in_sizes, int n_in,
                              void* d_out, int out_size, void* d_ws, size_t ws_size,
                              hipStream_t stream) {
    const float* xyzs  = (const float*)d_in[0];
    const float* feats = (const float*)d_in[1];
    const float* w1 = (const float*)d_in[2];
    const float* b1 = (const float*)d_in[3];
    const float* w2 = (const float*)d_in[4];
    const float* b2 = (const float*)d_in[5];
    const float* w3 = (const float*)d_in[6];
    const float* b3 = (const float*)d_in[7];

    float* out_anchor = (float*)d_out;
    float* out_feat = out_anchor + (size_t)BB * TT * MM * 3;

    char* ws = (char*)d_ws;
    int* fps_idx = (int*)ws;                                   // 64 KB
    int* idxk = (int*)(ws + 65536);                            // 2 MB
    _Float16* Pp = (_Float16*)(ws + 65536 + 2097152);          // B*T*N*128 fp16 = 16 MB
    float* Qp = (float*)(ws + 65536 + 2097152 + 16777216);     // B*T*M*128 fp32 = 8 MB
    if (ws_size < (size_t)(65536 + 2097152 + 16777216) + (size_t)BB * TT * MM * 128 * 4)
        return;

    (void)hipFuncSetAttribute((const void*)k_fps_pp, hipFuncAttributeMaxDynamicSharedMemorySize, FPP_LDS);
    k_fps_pp<<<BB * TT + BB * TT * NN / 64, 256, FPP_LDS, stream>>>(xyzs, feats, w1, fps_idx, Pp);
    k_knn<<<BB * TT * 64, 256, 0, stream>>>(xyzs, fps_idx, idxk);
    k_qp<<<BB * TT * MM / 64, 256, 0, stream>>>(xyzs, feats, w1, b1, fps_idx, Qp, out_anchor);

    (void)hipFuncSetAttribute((const void*)k_mlp, hipFuncAttributeMaxDynamicSharedMemorySize, SM_TOTAL);
    k_mlp<<<256, 1024, SM_TOTAL, stream>>>(Pp, Qp, idxk, w2, b2, w3, b3, out_feat);
}